// Round 1
// baseline (10291.766 us; speedup 1.0000x reference)
//
#include <hip/hip_runtime.h>
#include <stdint.h>

// ---------------- problem constants ----------------
#define B_   256
#define T_   512
#define CIN  64
#define H_   256
#define G4   1024   // 4*H
#define NC   6

// ---------------- WG geometry ----------------------
#define MB   32               // batch rows per WG
#define NHU  16               // hidden units per WG
#define NBG  (B_/MB)          // 8 batch groups
#define NHG  (H_/NHU)         // 16 hidden groups
#define NWG  (NBG*NHG)        // 128 workgroups

typedef __bf16 bf16x8 __attribute__((ext_vector_type(8)));
typedef __bf16 bf16x4 __attribute__((ext_vector_type(4)));
typedef float  f32x4  __attribute__((ext_vector_type(4)));

// ---------------- workspace layout (bytes) ---------
#define OFF_XBF   ((size_t)0)
#define SZ_XBF    ((size_t)B_*T_*CIN*2)          // 16 MB
#define OFF_W0X   (OFF_XBF + SZ_XBF)
#define SZ_W0X    ((size_t)G4*CIN*2)             // 128 KB
#define OFF_W0H   (OFF_W0X + SZ_W0X)
#define SZ_WH     ((size_t)G4*H_*2)              // 512 KB
#define OFF_W1X   (OFF_W0H + SZ_WH)
#define OFF_W1H   (OFF_W1X + SZ_WH)
#define OFF_B0    (OFF_W1H + SZ_WH)
#define OFF_B1    (OFF_B0 + 4096)
#define OFF_APUB  (OFF_B1 + 4096)
#define SZ_PUB    ((size_t)2*B_*H_*2)            // 256 KB (2 slots)
#define OFF_BPUB  (OFF_APUB + SZ_PUB)
#define OFF_FLAGS (OFF_BPUB + SZ_PUB)

#define DYN_LDS_ELEMS (4096 + 3*16384)           // 53248 bf16
#define DYN_LDS_BYTES (DYN_LDS_ELEMS*2)          // 106496 B

__device__ __forceinline__ f32x4 MFMA(bf16x8 a, bf16x8 b, f32x4 c) {
  return __builtin_amdgcn_mfma_f32_16x16x32_bf16(a, b, c, 0, 0, 0);
}
__device__ __forceinline__ float fsig(float x) { return 1.f/(1.f + __expf(-x)); }
__device__ __forceinline__ float ftanh_(float x) {
  float xx = fminf(fmaxf(x, -15.f), 15.f);
  float t = __expf(2.f*xx);
  return (t-1.f)/(t+1.f);
}

// ---------------- prep: x -> bf16 ------------------
__global__ void k_prep_x(const float* __restrict__ x, __bf16* __restrict__ xbf) {
  int i = blockIdx.x * blockDim.x + threadIdx.x;
  const int n4 = (B_*T_*CIN)/4;
  if (i >= n4) return;
  float4 v = reinterpret_cast<const float4*>(x)[i];
  bf16x4 o;
  o[0] = (__bf16)v.x; o[1] = (__bf16)v.y; o[2] = (__bf16)v.z; o[3] = (__bf16)v.w;
  reinterpret_cast<bf16x4*>(xbf)[i] = o;
}

// ---------------- prep: weights into MFMA-fragment order ----------------
// target layout per matrix: [hj][ct][ks][sub][col][j]  (j=8 contiguous bf16 = one lane's 16B)
// element = W[g=ct*256+hj*16+col][k=ks*32+sub*8+j]
__global__ void k_prep_w(const float* __restrict__ Wih0, const float* __restrict__ Whh0,
                         const float* __restrict__ Wih1, const float* __restrict__ Whh1,
                         __bf16* __restrict__ w0x, __bf16* __restrict__ w0h,
                         __bf16* __restrict__ w1x, __bf16* __restrict__ w1h) {
  int e = blockIdx.x * blockDim.x + threadIdx.x;
  const int E0 = G4*CIN, E1 = G4*H_;
  const float* W; __bf16* dst; int K; int idx;
  if      (e < E0)        { W = Wih0; dst = w0x; K = CIN; idx = e; }
  else if (e < E0+E1)     { W = Whh0; dst = w0h; K = H_;  idx = e - E0; }
  else if (e < E0+2*E1)   { W = Wih1; dst = w1x; K = H_;  idx = e - E0 - E1; }
  else if (e < E0+3*E1)   { W = Whh1; dst = w1h; K = H_;  idx = e - E0 - 2*E1; }
  else return;
  const int kb = K >> 5;                  // K/32
  int j   = idx & 7;
  int cl  = (idx >> 3) & 15;
  int sb  = (idx >> 7) & 3;
  int ks  = (idx >> 9) % kb;
  int ct  = (idx / (512*kb)) & 3;
  int hj  =  idx / (2048*kb);
  int g  = ct*256 + hj*16 + cl;
  int kk = ks*32 + sb*8 + j;
  dst[idx] = (__bf16)W[(size_t)g*K + kk];
}

// ---------------- prep: biases, zero pub buffers, zero flags ----------------
__global__ void k_prep_misc(const float* __restrict__ bih0, const float* __restrict__ bhh0,
                            const float* __restrict__ bih1, const float* __restrict__ bhh1,
                            float* __restrict__ bias0, float* __restrict__ bias1,
                            unsigned* __restrict__ zbase, unsigned* __restrict__ flags) {
  int i = blockIdx.x * blockDim.x + threadIdx.x;
  if (i < G4) bias0[i] = bih0[i] + bhh0[i];
  else if (i < 2*G4) { int j = i - G4; bias1[j] = bih1[j] + bhh1[j]; }
  int zi = i - 2*G4;
  if (zi >= 0 && zi < (int)((2*SZ_PUB)/4)) zbase[zi] = 0u;   // apub+bpub contiguous
  if (i < 128) flags[i] = 0u;
}

// ---------------- persistent pipelined LSTM ----------------
__global__ void __launch_bounds__(256, 1) k_lstm(
    const __bf16* __restrict__ xbf,
    const __bf16* __restrict__ w0x_g, const __bf16* __restrict__ w0h_g,
    const __bf16* __restrict__ w1x_g, const __bf16* __restrict__ w1h_g,
    const float* __restrict__ bias0, const float* __restrict__ bias1,
    __bf16* __restrict__ apub, __bf16* __restrict__ bpub,
    unsigned* __restrict__ flags,
    const float* __restrict__ Wfc, const float* __restrict__ bfc,
    float* __restrict__ out)
{
  extern __shared__ __bf16 lds[];
  __bf16* l0x = lds;                 // 4096  elems
  __bf16* l0h = lds + 4096;          // 16384
  __bf16* l1x = lds + 20480;         // 16384
  __bf16* l1h = lds + 36864;         // 16384
  __shared__ float s_log[MB][NC];

  const int tid   = threadIdx.x;
  const int bid   = blockIdx.x;
  const int bg    = bid >> 4;        // 0..7  batch group (32 rows)
  const int hj    = bid & 15;        // 0..15 hidden group (16 units)
  const int wave  = tid >> 6;
  const int lane  = tid & 63;
  const int layer = wave >> 1;       // waves 0,1 -> layer0 ; waves 2,3 -> layer1
  const int mt    = wave & 1;        // m-tile within the 32-row batch group
  const int col   = lane & 15;       // MFMA n / A-row index
  const int sub   = lane >> 4;       // MFMA k-group
  const int brow  = bg*MB + mt*16;

  // stage weights LDS-resident for the whole run
  {
    const uint4* s; uint4* d;
    s = (const uint4*)(w0x_g + (size_t)hj*4096);  d = (uint4*)l0x;
    for (int i = tid; i < 512;  i += 256) d[i] = s[i];
    s = (const uint4*)(w0h_g + (size_t)hj*16384); d = (uint4*)l0h;
    for (int i = tid; i < 2048; i += 256) d[i] = s[i];
    s = (const uint4*)(w1x_g + (size_t)hj*16384); d = (uint4*)l1x;
    for (int i = tid; i < 2048; i += 256) d[i] = s[i];
    s = (const uint4*)(w1h_g + (size_t)hj*16384); d = (uint4*)l1h;
    for (int i = tid; i < 2048; i += 256) d[i] = s[i];
  }
  __syncthreads();

  // per-lane gate biases (unit = hj*16+col), per this wave's layer
  float bs0, bs1, bs2, bs3;
  {
    const float* bp = layer ? bias1 : bias0;
    bs0 = bp[0*256 + hj*16 + col];
    bs1 = bp[1*256 + hj*16 + col];
    bs2 = bp[2*256 + hj*16 + col];
    bs3 = bp[3*256 + hj*16 + col];
  }
  float cst[4] = {0.f, 0.f, 0.f, 0.f};   // c-state for this lane's 4 (row,unit) cells
  unsigned* cntp = flags + (size_t)bg*16; // 64B-spaced per-bg rendezvous counter

  for (int k = 0; k <= T_; ++k) {
    const __bf16* a_prev = apub + (size_t)((k+1)&1)*(B_*H_);
    const __bf16* b_prev = bpub + (size_t)((k+1)&1)*(B_*H_);
    __bf16* a_cur = apub + (size_t)(k&1)*(B_*H_);
    __bf16* b_cur = bpub + (size_t)(k&1)*(B_*H_);
    const bool act0 = (layer == 0) && (k < T_);
    const bool act1 = (layer == 1) && (k >= 1);
    f32x4 acc0 = {0,0,0,0}, acc1 = {0,0,0,0}, acc2 = {0,0,0,0}, acc3 = {0,0,0,0};

    // phase A (no dependence on published data): x-input GEMM, K=64
    if (act0) {
      const __bf16* xr = xbf + ((size_t)(brow+col)*T_ + k)*CIN + sub*8;
      const __bf16* wb = l0x + sub*128 + col*8;
#pragma unroll
      for (int ks = 0; ks < 2; ++ks) {
        bf16x8 a = *(const bf16x8*)(xr + ks*32);
        acc0 = MFMA(a, *(const bf16x8*)(wb + ks*512 +    0), acc0);
        acc1 = MFMA(a, *(const bf16x8*)(wb + ks*512 + 1024), acc1);
        acc2 = MFMA(a, *(const bf16x8*)(wb + ks*512 + 2048), acc2);
        acc3 = MFMA(a, *(const bf16x8*)(wb + ks*512 + 3072), acc3);
      }
    }

    // rendezvous: wait until all 16 WGs of this bg finished iteration k-1
    if (k > 0) {
      __syncthreads();
      if (tid == 0) {
        const unsigned tgt = 16u * (unsigned)k;
        while (__hip_atomic_load(cntp, __ATOMIC_RELAXED, __HIP_MEMORY_SCOPE_AGENT) < tgt)
          __builtin_amdgcn_s_sleep(1);
      }
      __syncthreads();
      __builtin_amdgcn_fence(__ATOMIC_ACQUIRE, "agent");
    }

    // phase B: recurrent GEMMs
    if (act0) {            // gates0 += a_{k-1} @ Whh0^T
      const __bf16* ar = a_prev + (size_t)(brow+col)*H_ + sub*8;
      const __bf16* wb = l0h + sub*128 + col*8;
#pragma unroll
      for (int ks = 0; ks < 8; ++ks) {
        bf16x8 a = *(const bf16x8*)(ar + ks*32);
        acc0 = MFMA(a, *(const bf16x8*)(wb + ks*512 +     0), acc0);
        acc1 = MFMA(a, *(const bf16x8*)(wb + ks*512 +  4096), acc1);
        acc2 = MFMA(a, *(const bf16x8*)(wb + ks*512 +  8192), acc2);
        acc3 = MFMA(a, *(const bf16x8*)(wb + ks*512 + 12288), acc3);
      }
    } else if (act1) {     // gates1 = a_{k-1} @ Wih1^T + b_{k-2} @ Whh1^T
      const __bf16* ar = a_prev + (size_t)(brow+col)*H_ + sub*8;
      const __bf16* w1 = l1x + sub*128 + col*8;
#pragma unroll
      for (int ks = 0; ks < 8; ++ks) {
        bf16x8 a = *(const bf16x8*)(ar + ks*32);
        acc0 = MFMA(a, *(const bf16x8*)(w1 + ks*512 +     0), acc0);
        acc1 = MFMA(a, *(const bf16x8*)(w1 + ks*512 +  4096), acc1);
        acc2 = MFMA(a, *(const bf16x8*)(w1 + ks*512 +  8192), acc2);
        acc3 = MFMA(a, *(const bf16x8*)(w1 + ks*512 + 12288), acc3);
      }
      const __bf16* br = b_prev + (size_t)(brow+col)*H_ + sub*8;
      const __bf16* w2 = l1h + sub*128 + col*8;
#pragma unroll
      for (int ks = 0; ks < 8; ++ks) {
        bf16x8 a = *(const bf16x8*)(br + ks*32);
        acc0 = MFMA(a, *(const bf16x8*)(w2 + ks*512 +     0), acc0);
        acc1 = MFMA(a, *(const bf16x8*)(w2 + ks*512 +  4096), acc1);
        acc2 = MFMA(a, *(const bf16x8*)(w2 + ks*512 +  8192), acc2);
        acc3 = MFMA(a, *(const bf16x8*)(w2 + ks*512 + 12288), acc3);
      }
    }

    // elementwise LSTM cell + publish h (bf16)
    if (act0 || act1) {
      __bf16* dst  = act0 ? a_cur : b_cur;
      __bf16* drow = dst + (size_t)(brow + sub*4)*H_ + hj*NHU + col;
#pragma unroll
      for (int q = 0; q < 4; ++q) {
        float gi = acc0[q] + bs0;
        float gf = acc1[q] + bs1;
        float gg = acc2[q] + bs2;
        float go = acc3[q] + bs3;
        float si = fsig(gi), sf = fsig(gf), sg = ftanh_(gg), so = fsig(go);
        float c = sf*cst[q] + si*sg;
        cst[q] = c;
        drow[(size_t)q*H_] = (__bf16)(so * ftanh_(c));
      }
    }

    // arrive
    __builtin_amdgcn_fence(__ATOMIC_RELEASE, "agent");
    __syncthreads();
    if (tid == 0)
      __hip_atomic_fetch_add(cntp, 1u, __ATOMIC_RELAXED, __HIP_MEMORY_SCOPE_AGENT);
  }

  // ---------------- final FC + softmax (one WG per batch group) ----------------
  if (hj == 0) {
    if (tid == 0) {
      const unsigned tgt = 16u * (unsigned)(T_ + 1);
      while (__hip_atomic_load(cntp, __ATOMIC_RELAXED, __HIP_MEMORY_SCOPE_AGENT) < tgt)
        __builtin_amdgcn_s_sleep(1);
    }
    __syncthreads();
    __builtin_amdgcn_fence(__ATOMIC_ACQUIRE, "agent");
    // b_{T-1} lives in bpub slot (T_ & 1) == 0
    if (tid < MB*NC) {
      int r = tid / NC, cl = tid % NC;
      const __bf16* hr = bpub + (size_t)(bg*MB + r)*H_;
      const float*  wr = Wfc + (size_t)cl*H_;
      float s = bfc[cl];
      for (int j2 = 0; j2 < H_; ++j2) s = fmaf((float)hr[j2], wr[j2], s);
      s_log[r][cl] = s;
    }
    __syncthreads();
    if (tid < MB) {
      float mx = s_log[tid][0];
#pragma unroll
      for (int c2 = 1; c2 < NC; ++c2) mx = fmaxf(mx, s_log[tid][c2]);
      float e[NC]; float se = 0.f;
#pragma unroll
      for (int c2 = 0; c2 < NC; ++c2) { e[c2] = __expf(s_log[tid][c2] - mx); se += e[c2]; }
      float inv = 1.f/se;
#pragma unroll
      for (int c2 = 0; c2 < NC; ++c2) out[(size_t)(bg*MB + tid)*NC + c2] = e[c2]*inv;
    }
  }
}

// ---------------- host launcher ----------------
extern "C" void kernel_launch(void* const* d_in, const int* in_sizes, int n_in,
                              void* d_out, int out_size, void* d_ws, size_t ws_size,
                              hipStream_t stream) {
  const float* x    = (const float*)d_in[0];
  const float* Wih0 = (const float*)d_in[1];
  const float* Whh0 = (const float*)d_in[2];
  const float* bih0 = (const float*)d_in[3];
  const float* bhh0 = (const float*)d_in[4];
  const float* Wih1 = (const float*)d_in[5];
  const float* Whh1 = (const float*)d_in[6];
  const float* bih1 = (const float*)d_in[7];
  const float* bhh1 = (const float*)d_in[8];
  const float* Wfc  = (const float*)d_in[9];
  const float* bfc  = (const float*)d_in[10];
  float* out = (float*)d_out;
  char*  ws  = (char*)d_ws;

  __bf16* xbf  = (__bf16*)(ws + OFF_XBF);
  __bf16* w0x  = (__bf16*)(ws + OFF_W0X);
  __bf16* w0h  = (__bf16*)(ws + OFF_W0H);
  __bf16* w1x  = (__bf16*)(ws + OFF_W1X);
  __bf16* w1h  = (__bf16*)(ws + OFF_W1H);
  float*  b0   = (float*) (ws + OFF_B0);
  float*  b1   = (float*) (ws + OFF_B1);
  __bf16* apub = (__bf16*)(ws + OFF_APUB);
  __bf16* bpub = (__bf16*)(ws + OFF_BPUB);
  unsigned* flags = (unsigned*)(ws + OFF_FLAGS);

  {
    const int n4 = (B_*T_*CIN)/4;
    k_prep_x<<<(n4 + 255)/256, 256, 0, stream>>>(x, xbf);
  }
  {
    const int tot = G4*CIN + 3*G4*H_;
    k_prep_w<<<(tot + 255)/256, 256, 0, stream>>>(Wih0, Whh0, Wih1, Whh1, w0x, w0h, w1x, w1h);
  }
  {
    const int tot = 2*G4 + (int)((2*SZ_PUB)/4);
    k_prep_misc<<<(tot + 255)/256, 256, 0, stream>>>(bih0, bhh0, bih1, bhh1, b0, b1,
                                                     (unsigned*)apub, flags);
  }
  (void)hipFuncSetAttribute((const void*)k_lstm,
                            hipFuncAttributeMaxDynamicSharedMemorySize, DYN_LDS_BYTES);
  k_lstm<<<NWG, 256, DYN_LDS_BYTES, stream>>>(xbf, w0x, w0h, w1x, w1h, b0, b1,
                                              apub, bpub, flags, Wfc, bfc, out);
}

// Round 2
// 2460.233 us; speedup vs baseline: 4.1832x; 4.1832x over previous
//
#include <hip/hip_runtime.h>
#include <stdint.h>

// ---------------- problem constants ----------------
#define B_   256
#define T_   512
#define CIN  64
#define H_   256
#define G4   1024   // 4*H
#define NC   6

// ---------------- WG geometry ----------------------
#define MB   32               // batch rows per WG
#define NHU  16               // hidden units per WG
#define NBG  (B_/MB)          // 8 batch groups
#define NHG  (H_/NHU)         // 16 hidden groups
#define NWG  (NBG*NHG)        // 128 workgroups

typedef __bf16 bf16x8 __attribute__((ext_vector_type(8)));
typedef __bf16 bf16x4 __attribute__((ext_vector_type(4)));
typedef float  f32x4  __attribute__((ext_vector_type(4)));

// ---------------- workspace layout (bytes) ---------
#define OFF_XBF   ((size_t)0)
#define SZ_XBF    ((size_t)B_*T_*CIN*2)          // 16 MB
#define OFF_W0X   (OFF_XBF + SZ_XBF)
#define SZ_W0X    ((size_t)G4*CIN*2)             // 128 KB
#define OFF_W0H   (OFF_W0X + SZ_W0X)
#define SZ_WH     ((size_t)G4*H_*2)              // 512 KB
#define OFF_W1X   (OFF_W0H + SZ_WH)
#define OFF_W1H   (OFF_W1X + SZ_WH)
#define OFF_B0    (OFF_W1H + SZ_WH)
#define OFF_B1    (OFF_B0 + 4096)
#define OFF_APUB  (OFF_B1 + 4096)
#define SZ_PUB    ((size_t)2*B_*H_*2)            // 256 KB (2 slots)
#define OFF_BPUB  (OFF_APUB + SZ_PUB)
#define OFF_FLAGS (OFF_BPUB + SZ_PUB)

#define DYN_LDS_ELEMS (4096 + 3*16384)           // 53248 bf16
#define DYN_LDS_BYTES (DYN_LDS_ELEMS*2)          // 106496 B

__device__ __forceinline__ f32x4 MFMA(bf16x8 a, bf16x8 b, f32x4 c) {
  return __builtin_amdgcn_mfma_f32_16x16x32_bf16(a, b, c, 0, 0, 0);
}
__device__ __forceinline__ float fsig(float x) { return 1.f/(1.f + __expf(-x)); }
__device__ __forceinline__ float ftanh_(float x) {
  float xx = fminf(fmaxf(x, -15.f), 15.f);
  float t = __expf(2.f*xx);
  return (t-1.f)/(t+1.f);
}

// coherent (coherence-point) 8x16B batched load, no wait inside
__device__ __forceinline__ void load8_sys(const __bf16* b, bf16x8 (&r)[8]) {
  const __bf16 *p0=b,      *p1=b+32,  *p2=b+64,  *p3=b+96,
               *p4=b+128,  *p5=b+160, *p6=b+192, *p7=b+224;
  asm volatile(
    "global_load_dwordx4 %0, %8, off sc0 sc1\n\t"
    "global_load_dwordx4 %1, %9, off sc0 sc1\n\t"
    "global_load_dwordx4 %2, %10, off sc0 sc1\n\t"
    "global_load_dwordx4 %3, %11, off sc0 sc1\n\t"
    "global_load_dwordx4 %4, %12, off sc0 sc1\n\t"
    "global_load_dwordx4 %5, %13, off sc0 sc1\n\t"
    "global_load_dwordx4 %6, %14, off sc0 sc1\n\t"
    "global_load_dwordx4 %7, %15, off sc0 sc1"
    : "=&v"(r[0]), "=&v"(r[1]), "=&v"(r[2]), "=&v"(r[3]),
      "=&v"(r[4]), "=&v"(r[5]), "=&v"(r[6]), "=&v"(r[7])
    : "v"(p0), "v"(p1), "v"(p2), "v"(p3), "v"(p4), "v"(p5), "v"(p6), "v"(p7)
    : "memory");
}
__device__ __forceinline__ void waitv0() { asm volatile("s_waitcnt vmcnt(0)" ::: "memory"); }
__device__ __forceinline__ void sbar0()  { __builtin_amdgcn_sched_barrier(0); }
// write-through no-allocate 2B store to the coherence point
__device__ __forceinline__ void store_h16(__bf16* p, float v) {
  __bf16 h = (__bf16)v;
  unsigned u = (unsigned)__builtin_bit_cast(unsigned short, h);
  asm volatile("global_store_short %0, %1, off sc0 sc1 nt" :: "v"(p), "v"(u) : "memory");
}

// ---------------- prep: x -> bf16 ------------------
__global__ void k_prep_x(const float* __restrict__ x, __bf16* __restrict__ xbf) {
  int i = blockIdx.x * blockDim.x + threadIdx.x;
  const int n4 = (B_*T_*CIN)/4;
  if (i >= n4) return;
  float4 v = reinterpret_cast<const float4*>(x)[i];
  bf16x4 o;
  o[0] = (__bf16)v.x; o[1] = (__bf16)v.y; o[2] = (__bf16)v.z; o[3] = (__bf16)v.w;
  reinterpret_cast<bf16x4*>(xbf)[i] = o;
}

// ---------------- prep: weights into MFMA-fragment order ----------------
// target layout per matrix: [hj][ct][ks][sub][col][j]  (j=8 contiguous bf16)
// element = W[g=ct*256+hj*16+col][k=ks*32+sub*8+j]
__global__ void k_prep_w(const float* __restrict__ Wih0, const float* __restrict__ Whh0,
                         const float* __restrict__ Wih1, const float* __restrict__ Whh1,
                         __bf16* __restrict__ w0x, __bf16* __restrict__ w0h,
                         __bf16* __restrict__ w1x, __bf16* __restrict__ w1h) {
  int e = blockIdx.x * blockDim.x + threadIdx.x;
  const int E0 = G4*CIN, E1 = G4*H_;
  const float* W; __bf16* dst; int K; int idx;
  if      (e < E0)        { W = Wih0; dst = w0x; K = CIN; idx = e; }
  else if (e < E0+E1)     { W = Whh0; dst = w0h; K = H_;  idx = e - E0; }
  else if (e < E0+2*E1)   { W = Wih1; dst = w1x; K = H_;  idx = e - E0 - E1; }
  else if (e < E0+3*E1)   { W = Whh1; dst = w1h; K = H_;  idx = e - E0 - 2*E1; }
  else return;
  const int kb = K >> 5;                  // K/32
  int j   = idx & 7;
  int cl  = (idx >> 3) & 15;
  int sb  = (idx >> 7) & 3;
  int ks  = (idx >> 9) % kb;
  int ct  = (idx / (512*kb)) & 3;
  int hj  =  idx / (2048*kb);
  int g  = ct*256 + hj*16 + cl;
  int kk = ks*32 + sb*8 + j;
  dst[idx] = (__bf16)W[(size_t)g*K + kk];
}

// ---------------- prep: biases, zero pub buffers, zero flags ----------------
__global__ void k_prep_misc(const float* __restrict__ bih0, const float* __restrict__ bhh0,
                            const float* __restrict__ bih1, const float* __restrict__ bhh1,
                            float* __restrict__ bias0, float* __restrict__ bias1,
                            unsigned* __restrict__ zbase, unsigned* __restrict__ flags) {
  int i = blockIdx.x * blockDim.x + threadIdx.x;
  if (i < G4) bias0[i] = bih0[i] + bhh0[i];
  else if (i < 2*G4) { int j = i - G4; bias1[j] = bih1[j] + bhh1[j]; }
  int zi = i - 2*G4;
  if (zi >= 0 && zi < (int)((2*SZ_PUB)/4)) zbase[zi] = 0u;   // apub+bpub contiguous
  if (i < 128) flags[i] = 0u;
}

// ---------------- persistent pipelined LSTM ----------------
__global__ void __launch_bounds__(256, 1) k_lstm(
    const __bf16* __restrict__ xbf,
    const __bf16* __restrict__ w0x_g, const __bf16* __restrict__ w0h_g,
    const __bf16* __restrict__ w1x_g, const __bf16* __restrict__ w1h_g,
    const float* __restrict__ bias0, const float* __restrict__ bias1,
    __bf16* __restrict__ apub, __bf16* __restrict__ bpub,
    unsigned* __restrict__ flags,
    const float* __restrict__ Wfc, const float* __restrict__ bfc,
    float* __restrict__ out)
{
  extern __shared__ __bf16 lds[];
  __bf16* l0x = lds;                 // 4096  elems
  __bf16* l0h = lds + 4096;          // 16384
  __bf16* l1x = lds + 20480;         // 16384
  __bf16* l1h = lds + 36864;         // 16384
  __shared__ float s_log[MB][NC];

  const int tid   = threadIdx.x;
  const int bid   = blockIdx.x;
  const int bg    = bid & 7;         // bg = bid%8: 16 WGs of a bg land on one XCD (perf hint)
  const int hj    = bid >> 3;        // 0..15 hidden group (16 units)
  const int wave  = tid >> 6;
  const int lane  = tid & 63;
  const int layer = wave >> 1;       // waves 0,1 -> layer0 ; waves 2,3 -> layer1
  const int mt    = wave & 1;        // m-tile within the 32-row batch group
  const int col   = lane & 15;       // MFMA n / A-row index
  const int sub   = lane >> 4;       // MFMA k-group
  const int brow  = bg*MB + mt*16;

  // stage weights LDS-resident for the whole run
  {
    const uint4* s; uint4* d;
    s = (const uint4*)(w0x_g + (size_t)hj*4096);  d = (uint4*)l0x;
    for (int i = tid; i < 512;  i += 256) d[i] = s[i];
    s = (const uint4*)(w0h_g + (size_t)hj*16384); d = (uint4*)l0h;
    for (int i = tid; i < 2048; i += 256) d[i] = s[i];
    s = (const uint4*)(w1x_g + (size_t)hj*16384); d = (uint4*)l1x;
    for (int i = tid; i < 2048; i += 256) d[i] = s[i];
    s = (const uint4*)(w1h_g + (size_t)hj*16384); d = (uint4*)l1h;
    for (int i = tid; i < 2048; i += 256) d[i] = s[i];
  }
  __syncthreads();

  // per-lane gate biases (unit = hj*16+col), per this wave's layer
  float bs0, bs1, bs2, bs3;
  {
    const float* bp = layer ? bias1 : bias0;
    bs0 = bp[0*256 + hj*16 + col];
    bs1 = bp[1*256 + hj*16 + col];
    bs2 = bp[2*256 + hj*16 + col];
    bs3 = bp[3*256 + hj*16 + col];
  }
  float cst[4] = {0.f, 0.f, 0.f, 0.f};   // c-state for this lane's 4 (row,unit) cells
  unsigned* cntp = flags + (size_t)bg*16; // 64B-spaced per-bg rendezvous counter

  for (int k = 0; k <= T_; ++k) {
    const __bf16* a_prev = apub + (size_t)((k+1)&1)*(B_*H_);
    const __bf16* b_prev = bpub + (size_t)((k+1)&1)*(B_*H_);
    __bf16* a_cur = apub + (size_t)(k&1)*(B_*H_);
    __bf16* b_cur = bpub + (size_t)(k&1)*(B_*H_);
    const bool act0 = (layer == 0) && (k < T_);
    const bool act1 = (layer == 1) && (k >= 1);
    f32x4 acc0 = {0,0,0,0}, acc1 = {0,0,0,0}, acc2 = {0,0,0,0}, acc3 = {0,0,0,0};

    // phase A (no dependence on published data): x-input GEMM, K=64
    if (act0) {
      const __bf16* xr = xbf + ((size_t)(brow+col)*T_ + k)*CIN + sub*8;
      const __bf16* wb = l0x + sub*128 + col*8;
#pragma unroll
      for (int ks = 0; ks < 2; ++ks) {
        bf16x8 a = *(const bf16x8*)(xr + ks*32);
        acc0 = MFMA(a, *(const bf16x8*)(wb + ks*512 +    0), acc0);
        acc1 = MFMA(a, *(const bf16x8*)(wb + ks*512 + 1024), acc1);
        acc2 = MFMA(a, *(const bf16x8*)(wb + ks*512 + 2048), acc2);
        acc3 = MFMA(a, *(const bf16x8*)(wb + ks*512 + 3072), acc3);
      }
    }

    // rendezvous: wait until all 16 WGs of this bg finished iteration k-1
    if (k > 0) {
      if (tid == 0) {
        const unsigned tgt = 16u * (unsigned)k;
        while (__hip_atomic_load(cntp, __ATOMIC_RELAXED, __HIP_MEMORY_SCOPE_AGENT) < tgt)
          __builtin_amdgcn_s_sleep(1);
      }
      __syncthreads();
    }

    // phase B: recurrent GEMMs (operands via coherence-point loads, no fences)
    if (act0) {            // gates0 += a_{k-1} @ Whh0^T
      bf16x8 ra[8];
      load8_sys(a_prev + (size_t)(brow+col)*H_ + sub*8, ra);
      waitv0(); sbar0();
      const __bf16* wb = l0h + sub*128 + col*8;
#pragma unroll
      for (int ks = 0; ks < 8; ++ks) {
        acc0 = MFMA(ra[ks], *(const bf16x8*)(wb + ks*512 +     0), acc0);
        acc1 = MFMA(ra[ks], *(const bf16x8*)(wb + ks*512 +  4096), acc1);
        acc2 = MFMA(ra[ks], *(const bf16x8*)(wb + ks*512 +  8192), acc2);
        acc3 = MFMA(ra[ks], *(const bf16x8*)(wb + ks*512 + 12288), acc3);
      }
    } else if (act1) {     // gates1 = a_{k-1} @ Wih1^T + b_{k-2} @ Whh1^T
      bf16x8 ra[8], rb[8];
      load8_sys(a_prev + (size_t)(brow+col)*H_ + sub*8, ra);
      load8_sys(b_prev + (size_t)(brow+col)*H_ + sub*8, rb);
      waitv0(); sbar0();
      const __bf16* w1 = l1x + sub*128 + col*8;
      const __bf16* w2 = l1h + sub*128 + col*8;
#pragma unroll
      for (int ks = 0; ks < 8; ++ks) {
        acc0 = MFMA(ra[ks], *(const bf16x8*)(w1 + ks*512 +     0), acc0);
        acc1 = MFMA(ra[ks], *(const bf16x8*)(w1 + ks*512 +  4096), acc1);
        acc2 = MFMA(ra[ks], *(const bf16x8*)(w1 + ks*512 +  8192), acc2);
        acc3 = MFMA(ra[ks], *(const bf16x8*)(w1 + ks*512 + 12288), acc3);
      }
#pragma unroll
      for (int ks = 0; ks < 8; ++ks) {
        acc0 = MFMA(rb[ks], *(const bf16x8*)(w2 + ks*512 +     0), acc0);
        acc1 = MFMA(rb[ks], *(const bf16x8*)(w2 + ks*512 +  4096), acc1);
        acc2 = MFMA(rb[ks], *(const bf16x8*)(w2 + ks*512 +  8192), acc2);
        acc3 = MFMA(rb[ks], *(const bf16x8*)(w2 + ks*512 + 12288), acc3);
      }
    }

    // elementwise LSTM cell + publish h (write-through bf16)
    if (act0 || act1) {
      __bf16* dst  = act0 ? a_cur : b_cur;
      __bf16* drow = dst + (size_t)(brow + sub*4)*H_ + hj*NHU + col;
#pragma unroll
      for (int q = 0; q < 4; ++q) {
        float gi = acc0[q] + bs0;
        float gf = acc1[q] + bs1;
        float gg = acc2[q] + bs2;
        float go = acc3[q] + bs3;
        float si = fsig(gi), sf = fsig(gf), sg = ftanh_(gg), so = fsig(go);
        float c = sf*cst[q] + si*sg;
        cst[q] = c;
        store_h16(drow + (size_t)q*H_, so * ftanh_(c));
      }
    }

    // arrive: drain own write-through stores, then one flag add per WG
    waitv0();
    __syncthreads();
    if (tid == 0)
      __hip_atomic_fetch_add(cntp, 1u, __ATOMIC_RELAXED, __HIP_MEMORY_SCOPE_AGENT);
  }

  // ---------------- final FC + softmax (one WG per batch group) ----------------
  if (hj == 0) {
    if (tid == 0) {
      const unsigned tgt = 16u * (unsigned)(T_ + 1);
      while (__hip_atomic_load(cntp, __ATOMIC_RELAXED, __HIP_MEMORY_SCOPE_AGENT) < tgt)
        __builtin_amdgcn_s_sleep(1);
    }
    __syncthreads();
    __builtin_amdgcn_fence(__ATOMIC_ACQUIRE, "agent");   // one-time, cheap here
    // b_{T-1} lives in bpub slot (T_ & 1) == 0
    if (tid < MB*NC) {
      int r = tid / NC, cl = tid % NC;
      const __bf16* hr = bpub + (size_t)(bg*MB + r)*H_;
      const float*  wr = Wfc + (size_t)cl*H_;
      float s = bfc[cl];
      for (int j2 = 0; j2 < H_; ++j2) s = fmaf((float)hr[j2], wr[j2], s);
      s_log[r][cl] = s;
    }
    __syncthreads();
    if (tid < MB) {
      float mx = s_log[tid][0];
#pragma unroll
      for (int c2 = 1; c2 < NC; ++c2) mx = fmaxf(mx, s_log[tid][c2]);
      float e[NC]; float se = 0.f;
#pragma unroll
      for (int c2 = 0; c2 < NC; ++c2) { e[c2] = __expf(s_log[tid][c2] - mx); se += e[c2]; }
      float inv = 1.f/se;
#pragma unroll
      for (int c2 = 0; c2 < NC; ++c2) out[(size_t)(bg*MB + tid)*NC + c2] = e[c2]*inv;
    }
  }
}

// ---------------- host launcher ----------------
extern "C" void kernel_launch(void* const* d_in, const int* in_sizes, int n_in,
                              void* d_out, int out_size, void* d_ws, size_t ws_size,
                              hipStream_t stream) {
  const float* x    = (const float*)d_in[0];
  const float* Wih0 = (const float*)d_in[1];
  const float* Whh0 = (const float*)d_in[2];
  const float* bih0 = (const float*)d_in[3];
  const float* bhh0 = (const float*)d_in[4];
  const float* Wih1 = (const float*)d_in[5];
  const float* Whh1 = (const float*)d_in[6];
  const float* bih1 = (const float*)d_in[7];
  const float* bhh1 = (const float*)d_in[8];
  const float* Wfc  = (const float*)d_in[9];
  const float* bfc  = (const float*)d_in[10];
  float* out = (float*)d_out;
  char*  ws  = (char*)d_ws;

  __bf16* xbf  = (__bf16*)(ws + OFF_XBF);
  __bf16* w0x  = (__bf16*)(ws + OFF_W0X);
  __bf16* w0h  = (__bf16*)(ws + OFF_W0H);
  __bf16* w1x  = (__bf16*)(ws + OFF_W1X);
  __bf16* w1h  = (__bf16*)(ws + OFF_W1H);
  float*  b0   = (float*) (ws + OFF_B0);
  float*  b1   = (float*) (ws + OFF_B1);
  __bf16* apub = (__bf16*)(ws + OFF_APUB);
  __bf16* bpub = (__bf16*)(ws + OFF_BPUB);
  unsigned* flags = (unsigned*)(ws + OFF_FLAGS);

  {
    const int n4 = (B_*T_*CIN)/4;
    k_prep_x<<<(n4 + 255)/256, 256, 0, stream>>>(x, xbf);
  }
  {
    const int tot = G4*CIN + 3*G4*H_;
    k_prep_w<<<(tot + 255)/256, 256, 0, stream>>>(Wih0, Whh0, Wih1, Whh1, w0x, w0h, w1x, w1h);
  }
  {
    const int tot = 2*G4 + (int)((2*SZ_PUB)/4);
    k_prep_misc<<<(tot + 255)/256, 256, 0, stream>>>(bih0, bhh0, bih1, bhh1, b0, b1,
                                                     (unsigned*)apub, flags);
  }
  (void)hipFuncSetAttribute((const void*)k_lstm,
                            hipFuncAttributeMaxDynamicSharedMemorySize, DYN_LDS_BYTES);
  k_lstm<<<NWG, 256, DYN_LDS_BYTES, stream>>>(xbf, w0x, w0h, w1x, w1h, b0, b1,
                                              apub, bpub, flags, Wfc, bfc, out);
}